// Round 7
// baseline (704.932 us; speedup 1.0000x reference)
//
#include <hip/hip_runtime.h>
#include <math.h>

// ---------------------------------------------------------------------------
// VQ-VAE encoder. Round 7: convs unchanged (r5 3-term split-bf16 MFMA).
// vq split: vq_argmax (MFMA distances -> idx/counts, ~15us) + vq_write
// (4096-block streaming writer for zq/loss/encodings via nontemporal
// stores -> tests the pure-write ceiling; r6's monolithic kernel ran the
// 134MB enc stream at only 0.68 TB/s).
// ---------------------------------------------------------------------------

typedef short short8 __attribute__((ext_vector_type(8)));
typedef float f32x4 __attribute__((ext_vector_type(4)));

__device__ __forceinline__ unsigned short bf16hi(float f) {
  unsigned u = __builtin_bit_cast(unsigned, f);
  return (unsigned short)((u + 0x7FFFu + ((u >> 16) & 1u)) >> 16);
}
__device__ __forceinline__ float bf16tof(unsigned short h) {
  unsigned u = ((unsigned)h) << 16;
  return __builtin_bit_cast(float, u);
}
__device__ __forceinline__ void split3(float f, unsigned short& h,
                                       unsigned short& m, unsigned short& l) {
  h = bf16hi(f);
  float r = f - bf16tof(h);
  m = bf16hi(r);
  l = bf16hi(r - bf16tof(m));
}
__device__ __forceinline__ void nt_store4(float* p, float a, float b,
                                          float c, float d) {
  f32x4 v = {a, b, c, d};
  __builtin_nontemporal_store(v, (f32x4*)p);
}

// ---------------------------------------------------------------------------
// conv kernel (unchanged from round 5)
// ---------------------------------------------------------------------------
template<int CIN, int TAPS, int S, bool RELU_IN, bool HAS_BIAS, bool RESID,
         bool CHW_IN, bool OUT_NOGUARD>
__global__ __launch_bounds__(256) void conv_mfma(
    const float* __restrict__ in, const short* __restrict__ Ab,
    const float* __restrict__ bias, const float* __restrict__ resid,
    float* __restrict__ out, int Tin, int Tout, int MTG)
{
  constexpr int nCk   = CIN / 32;
  constexpr int RS    = (S == 2) ? 130 : ((TAPS == 3) ? 66 : 64);
  constexpr int ROWBS = 40;

  __shared__ short xhi[RS * ROWBS];
  __shared__ short xmd[RS * ROWBS];
  __shared__ short xlo[RS * ROWBS];

  const int tid  = threadIdx.x;
  const int lane = tid & 63;
  const int wv   = tid >> 6;
  const int ih   = wv & 1;
  const int jh   = wv >> 1;
  const int tl   = lane & 15;
  const int q    = lane >> 4;
  const int b    = blockIdx.y;
  const int t0   = blockIdx.x * 64;
  const int co0  = blockIdx.z * 64;
  const int COUT = MTG * 16;

  const int rbase = (S == 2) ? (2 * t0) : ((TAPS == 3) ? t0 : (t0 + 1));

  f32x4 acc[2][2] = {};

  for (int ch = 0; ch < nCk; ch++) {
    if (ch) __syncthreads();

    if constexpr (!CHW_IN) {
      for (int i = tid; i < RS * 8; i += 256) {
        int rl = i >> 3;
        int c4 = (i & 7) * 4;
        int rg = rbase + rl;
        const float* sp = in + ((size_t)b * (Tin + 2) + rg) * CIN + ch * 32 + c4;
        float4 v = *(const float4*)sp;
        if (RELU_IN) {
          v.x = fmaxf(v.x, 0.f); v.y = fmaxf(v.y, 0.f);
          v.z = fmaxf(v.z, 0.f); v.w = fmaxf(v.w, 0.f);
        }
        float vv[4] = {v.x, v.y, v.z, v.w};
        unsigned short h[4], m[4], l[4];
        #pragma unroll
        for (int e = 0; e < 4; e++) split3(vv[e], h[e], m[e], l[e]);
        int slot = (S == 2) ? ((rl & 1) * 65 + (rl >> 1)) : rl;
        int off = slot * ROWBS + c4;
        uint2 uh, um, ul;
        uh.x = (unsigned)h[0] | ((unsigned)h[1] << 16);
        uh.y = (unsigned)h[2] | ((unsigned)h[3] << 16);
        um.x = (unsigned)m[0] | ((unsigned)m[1] << 16);
        um.y = (unsigned)m[2] | ((unsigned)m[3] << 16);
        ul.x = (unsigned)l[0] | ((unsigned)l[1] << 16);
        ul.y = (unsigned)l[2] | ((unsigned)l[3] << 16);
        *(uint2*)(xhi + off) = uh;
        *(uint2*)(xmd + off) = um;
        *(uint2*)(xlo + off) = ul;
      }
    } else {
      if (tid < 32) {
        int cig = ch * 32 + tid;
        int tin = 2 * t0 - 1;
        float v = 0.f;
        if (tin >= 0) v = in[((size_t)b * 64 + cig) * Tin + tin];
        unsigned short h, m, l;
        split3(v, h, m, l);
        xhi[tid] = (short)h;
        xmd[tid] = (short)m;
        xlo[tid] = (short)l;
      }
      int cil = tid >> 3, tq = tid & 7;
      for (int base = tq * 4; base <= 128; base += 32) {
        int tin0 = 2 * t0 + base;
        const float* sp = in + ((size_t)b * 64 + ch * 32 + cil) * Tin + tin0;
        float vv[4];
        if (tin0 + 3 < Tin) {
          float4 t4 = *(const float4*)sp;
          vv[0] = t4.x; vv[1] = t4.y; vv[2] = t4.z; vv[3] = t4.w;
        } else {
          #pragma unroll
          for (int e = 0; e < 4; e++) vv[e] = (tin0 + e < Tin) ? sp[e] : 0.f;
        }
        #pragma unroll
        for (int e = 0; e < 4; e++) {
          int rl = base + e + 1;
          if (rl <= 129) {
            unsigned short h, m, l;
            split3(vv[e], h, m, l);
            int slot = (rl & 1) * 65 + (rl >> 1);
            xhi[slot * ROWBS + cil] = (short)h;
            xmd[slot * ROWBS + cil] = (short)m;
            xlo[slot * ROWBS + cil] = (short)l;
          }
        }
      }
    }
    __syncthreads();

    #pragma unroll
    for (int tap = 0; tap < TAPS; tap++) {
      short8 ah[2], am[2], al[2];
      #pragma unroll
      for (int mi = 0; mi < 2; mi++) {
        const short* ab = Ab +
            (size_t)(((ch * TAPS + tap) * MTG + (co0 >> 4) + ih * 2 + mi) * 3) * 512
            + lane * 8;
        ah[mi] = *(const short8*)ab;
        am[mi] = *(const short8*)(ab + 512);
        al[mi] = *(const short8*)(ab + 1024);
      }
      #pragma unroll
      for (int nt = 0; nt < 2; nt++) {
        int tpos = jh * 32 + nt * 16 + tl;
        int slot;
        if constexpr (S == 2)         slot = (tap & 1) * 65 + tpos + (tap >> 1);
        else if constexpr (TAPS == 3) slot = tpos + tap;
        else                          slot = tpos;
        const int xo = slot * ROWBS + q * 8;
        short8 bh = *(const short8*)(xhi + xo);
        short8 bm = *(const short8*)(xmd + xo);
        short8 bl = *(const short8*)(xlo + xo);
        #pragma unroll
        for (int mi = 0; mi < 2; mi++) {
          acc[mi][nt] = __builtin_amdgcn_mfma_f32_16x16x32_bf16(ah[mi], bh, acc[mi][nt], 0, 0, 0);
          acc[mi][nt] = __builtin_amdgcn_mfma_f32_16x16x32_bf16(ah[mi], bm, acc[mi][nt], 0, 0, 0);
          acc[mi][nt] = __builtin_amdgcn_mfma_f32_16x16x32_bf16(am[mi], bh, acc[mi][nt], 0, 0, 0);
          acc[mi][nt] = __builtin_amdgcn_mfma_f32_16x16x32_bf16(am[mi], bm, acc[mi][nt], 0, 0, 0);
          acc[mi][nt] = __builtin_amdgcn_mfma_f32_16x16x32_bf16(ah[mi], bl, acc[mi][nt], 0, 0, 0);
          acc[mi][nt] = __builtin_amdgcn_mfma_f32_16x16x32_bf16(al[mi], bh, acc[mi][nt], 0, 0, 0);
        }
      }
    }
  }

  #pragma unroll
  for (int mi = 0; mi < 2; mi++) {
    #pragma unroll
    for (int nt = 0; nt < 2; nt++) {
      int t  = t0 + jh * 32 + nt * 16 + tl;
      int co = co0 + (ih * 2 + mi) * 16 + q * 4;
      f32x4 a = acc[mi][nt];
      float4 v = {a[0], a[1], a[2], a[3]};
      if constexpr (HAS_BIAS) {
        float4 bb = *(const float4*)(bias + co);
        v.x += bb.x; v.y += bb.y; v.z += bb.z; v.w += bb.w;
      }
      if constexpr (RESID) {
        float4 rr = *(const float4*)(resid + ((size_t)b * (Tout + 2) + t + 1) * COUT + co);
        v.x += rr.x; v.y += rr.y; v.z += rr.z; v.w += rr.w;
      }
      float* op;
      if constexpr (OUT_NOGUARD) op = out + ((size_t)b * Tout + t) * COUT + co;
      else                       op = out + ((size_t)b * (Tout + 2) + t + 1) * COUT + co;
      *(float4*)op = v;
    }
  }
}

// ---------------------------------------------------------------------------
// prep kernels (unchanged)
// ---------------------------------------------------------------------------
__global__ __launch_bounds__(256) void prep_small(
    const float* __restrict__ wout, const float* __restrict__ bout,
    const float* __restrict__ wpq, const float* __restrict__ bpq,
    const float* __restrict__ cb,
    float* __restrict__ Wc, float* __restrict__ bc, float* __restrict__ cnormd)
{
  const int tid = threadIdx.x;
  for (int i = tid; i < 64 * 128; i += 256) {
    int d = i >> 7, c = i & 127;
    float s = 0.f;
    for (int e = 0; e < 64; e++) s = fmaf(wpq[d * 64 + e], wout[e * 128 + c], s);
    Wc[i] = s;
  }
  for (int i = tid; i < 64; i += 256) {
    float s = bpq[i];
    for (int e = 0; e < 64; e++) s = fmaf(wpq[i * 64 + e], bout[e], s);
    bc[i] = s;
  }
  for (int k = tid; k < 512; k += 256) {
    float s = 0.f;
    for (int d = 0; d < 64; d++) { float c = cb[k * 64 + d]; s = fmaf(c, c, s); }
    cnormd[k] = -0.5f * s;
  }
}

__device__ __forceinline__ void buildA(const float* w, short* dst,
                                       int COUT, int CIN, int TAPS, int idx)
{
  int lane = idx & 63;
  int rest = idx >> 6;
  int hl   = rest % 3;  rest /= 3;
  int mtg  = rest % (COUT / 16); rest /= (COUT / 16);
  int tap  = rest % TAPS;
  int chunk = rest / TAPS;
  int co  = mtg * 16 + (lane & 15);
  int ci0 = chunk * 32 + (lane >> 4) * 8;
  short v[8];
  #pragma unroll
  for (int j = 0; j < 8; j++) {
    float f = w[((size_t)co * CIN + ci0 + j) * TAPS + tap];
    unsigned short h, m, l;
    split3(f, h, m, l);
    v[j] = (hl == 0) ? (short)h : ((hl == 1) ? (short)m : (short)l);
  }
  int MTG = COUT / 16;
  size_t o = ((((size_t)(chunk * TAPS + tap) * MTG + mtg) * 3 + hl) * 64 + lane) * 8;
  #pragma unroll
  for (int j = 0; j < 8; j++) dst[o + j] = v[j];
}

__device__ __forceinline__ void buildAcb(const float* cb, short* dst, int g)
{
  int lane = g & 63;
  int rest = g >> 6;
  int s  = rest % 3; rest /= 3;
  int kc = rest & 1;
  int ct = rest >> 1;
  int tl = lane & 15, q = lane >> 4;
  int code = ct * 16 + tl;
  int k0 = kc * 32 + q * 8;
  size_t o = (((size_t)(ct * 2 + kc) * 3 + s) * 64 + lane) * 8;
  #pragma unroll
  for (int j = 0; j < 8; j++) {
    float f = cb[(size_t)code * 64 + k0 + j];
    unsigned short h, m, l;
    split3(f, h, m, l);
    dst[o + j] = (s == 0) ? (short)h : ((s == 1) ? (short)m : (short)l);
  }
}

__global__ __launch_bounds__(256) void prep_w_all(
    const float* w1, const float* w2, const float* w3,
    const float* r0a, const float* r0b, const float* r1a, const float* r1b,
    const float* Wc, const float* cb,
    short* A1, short* A2, short* A3, short* A4, short* A5, short* A6,
    short* A7, short* A8, short* Acb)
{
  int g = blockIdx.x * 256 + threadIdx.x;
  if      (g < 6144)  buildA(w1,  A1, 64,  64,  4, g);
  else if (g < 18432) buildA(w2,  A2, 128, 64,  4, g - 6144);
  else if (g < 36864) buildA(w3,  A3, 128, 128, 3, g - 18432);
  else if (g < 46080) buildA(r0a, A4, 64,  128, 3, g - 36864);
  else if (g < 49152) buildA(r0b, A5, 128, 64,  1, g - 46080);
  else if (g < 58368) buildA(r1a, A6, 64,  128, 3, g - 49152);
  else if (g < 61440) buildA(r1b, A7, 128, 64,  1, g - 58368);
  else if (g < 64512) buildA(Wc,  A8, 64,  128, 1, g - 61440);
  else if (g < 76800) buildAcb(cb, Acb, g - 64512);
}

__global__ __launch_bounds__(256) void zero_guards(
    float* __restrict__ sA, float* __restrict__ sB1,
    float* __restrict__ sB2, float* __restrict__ sC)
{
  int gt = blockIdx.x * 256 + threadIdx.x;
  int NT = gridDim.x * 256;
  for (int i = gt; i < 64 * 2 * 64; i += NT) {
    int b = i >> 7, r = (i >> 6) & 1, c = i & 63;
    sA[((size_t)b * 2050 + r * 2049) * 64 + c] = 0.f;
  }
  for (int i = gt; i < 64 * 2 * 128; i += NT) {
    int b = i >> 8, r = (i >> 7) & 1, c = i & 127;
    size_t o = ((size_t)b * 1026 + r * 1025) * 128 + c;
    sB1[o] = 0.f; sB2[o] = 0.f;
  }
  for (int i = gt; i < 64 * 2 * 64; i += NT) {
    int b = i >> 7, r = (i >> 6) & 1, c = i & 63;
    sC[((size_t)b * 1026 + r * 1025) * 64 + c] = 0.f;
  }
}

// ---------------------------------------------------------------------------
// vq_argmax: 128 points/block, distances via MFMA, writes idx + counts only.
// ---------------------------------------------------------------------------
__global__ __launch_bounds__(256) void vq_argmax(
    const float* __restrict__ ze, const float* __restrict__ cnormd,
    const short* __restrict__ Acb,
    float* __restrict__ idx_out, int* __restrict__ idxw,
    int* __restrict__ counts)
{
  __shared__ short zh[128 * 72];
  __shared__ short zm[128 * 72];
  __shared__ short zl[128 * 72];

  const int tid  = threadIdx.x;
  const int lane = tid & 63;
  const int wv   = tid >> 6;
  const int tl   = lane & 15;
  const int q    = lane >> 4;
  const int n0   = blockIdx.x * 128;

  {
    const float* zb = ze + (size_t)n0 * 64;
    #pragma unroll
    for (int j = 0; j < 8; j++) {
      int off = j * 1024 + tid * 4;
      int p = off >> 6, d = off & 63;
      float2 v0 = *(const float2*)(zb + off);
      float2 v1 = *(const float2*)(zb + off + 2);
      float vv[4] = {v0.x, v0.y, v1.x, v1.y};
      unsigned short h[4], m[4], l[4];
      #pragma unroll
      for (int e = 0; e < 4; e++) split3(vv[e], h[e], m[e], l[e]);
      int o = p * 72 + d;
      uint2 uh, um, ul;
      uh.x = (unsigned)h[0] | ((unsigned)h[1] << 16);
      uh.y = (unsigned)h[2] | ((unsigned)h[3] << 16);
      um.x = (unsigned)m[0] | ((unsigned)m[1] << 16);
      um.y = (unsigned)m[2] | ((unsigned)m[3] << 16);
      ul.x = (unsigned)l[0] | ((unsigned)l[1] << 16);
      ul.y = (unsigned)l[2] | ((unsigned)l[3] << 16);
      *(uint2*)(zh + o) = uh;
      *(uint2*)(zm + o) = um;
      *(uint2*)(zl + o) = ul;
    }
  }
  __syncthreads();

  short8 bh[2][2], bm[2][2], bl[2][2];
  #pragma unroll
  for (int pt = 0; pt < 2; pt++) {
    int row = wv * 32 + pt * 16 + tl;
    #pragma unroll
    for (int kc = 0; kc < 2; kc++) {
      int o = row * 72 + kc * 32 + q * 8;
      bh[pt][kc] = *(const short8*)(zh + o);
      bm[pt][kc] = *(const short8*)(zm + o);
      bl[pt][kc] = *(const short8*)(zl + o);
    }
  }

  float best0 = -3.4e38f, best1 = -3.4e38f;
  int   bi0 = 0, bi1 = 0;

  for (int ct = 0; ct < 32; ct++) {
    float4 cv = *(const float4*)(cnormd + ct * 16 + q * 4);
    f32x4 a0 = {cv.x, cv.y, cv.z, cv.w};
    f32x4 a1 = a0;
    #pragma unroll
    for (int kc = 0; kc < 2; kc++) {
      const short* ap = Acb + (size_t)((ct * 2 + kc) * 3) * 512 + lane * 8;
      short8 ah = *(const short8*)ap;
      short8 am = *(const short8*)(ap + 512);
      short8 al = *(const short8*)(ap + 1024);
      a0 = __builtin_amdgcn_mfma_f32_16x16x32_bf16(ah, bh[0][kc], a0, 0, 0, 0);
      a1 = __builtin_amdgcn_mfma_f32_16x16x32_bf16(ah, bh[1][kc], a1, 0, 0, 0);
      a0 = __builtin_amdgcn_mfma_f32_16x16x32_bf16(ah, bm[0][kc], a0, 0, 0, 0);
      a1 = __builtin_amdgcn_mfma_f32_16x16x32_bf16(ah, bm[1][kc], a1, 0, 0, 0);
      a0 = __builtin_amdgcn_mfma_f32_16x16x32_bf16(am, bh[0][kc], a0, 0, 0, 0);
      a1 = __builtin_amdgcn_mfma_f32_16x16x32_bf16(am, bh[1][kc], a1, 0, 0, 0);
      a0 = __builtin_amdgcn_mfma_f32_16x16x32_bf16(am, bm[0][kc], a0, 0, 0, 0);
      a1 = __builtin_amdgcn_mfma_f32_16x16x32_bf16(am, bm[1][kc], a1, 0, 0, 0);
      a0 = __builtin_amdgcn_mfma_f32_16x16x32_bf16(ah, bl[0][kc], a0, 0, 0, 0);
      a1 = __builtin_amdgcn_mfma_f32_16x16x32_bf16(ah, bl[1][kc], a1, 0, 0, 0);
      a0 = __builtin_amdgcn_mfma_f32_16x16x32_bf16(al, bh[0][kc], a0, 0, 0, 0);
      a1 = __builtin_amdgcn_mfma_f32_16x16x32_bf16(al, bh[1][kc], a1, 0, 0, 0);
    }
    #pragma unroll
    for (int r = 0; r < 4; r++) {
      int code = ct * 16 + q * 4 + r;
      float v0 = a0[r], v1 = a1[r];
      if (v0 > best0) { best0 = v0; bi0 = code; }
      if (v1 > best1) { best1 = v1; bi1 = code; }
    }
  }

  #pragma unroll
  for (int mask = 16; mask <= 32; mask <<= 1) {
    float v0 = __shfl_xor(best0, mask, 64); int i0 = __shfl_xor(bi0, mask, 64);
    float v1 = __shfl_xor(best1, mask, 64); int i1 = __shfl_xor(bi1, mask, 64);
    if (v0 > best0 || (v0 == best0 && i0 < bi0)) { best0 = v0; bi0 = i0; }
    if (v1 > best1 || (v1 == best1 && i1 < bi1)) { best1 = v1; bi1 = i1; }
  }
  if (q == 0) {
    int p0 = wv * 32 + tl;
    int p1 = p0 + 16;
    idx_out[n0 + p0] = (float)bi0;
    idx_out[n0 + p1] = (float)bi1;
    idxw[n0 + p0] = bi0;
    idxw[n0 + p1] = bi1;
    atomicAdd(&counts[bi0], 1);
    atomicAdd(&counts[bi1], 1);
  }
}

// ---------------------------------------------------------------------------
// vq_write: 16 points/block, 4096 blocks. zq+loss (1 float4/thread) and
// encodings one-hot (8 float4/thread), all nontemporal streaming stores.
// ---------------------------------------------------------------------------
__global__ __launch_bounds__(256) void vq_write(
    const float* __restrict__ ze, const float* __restrict__ cb,
    const int* __restrict__ idxw,
    float* __restrict__ zq_out, float* __restrict__ enc,
    float* __restrict__ loss_accum)
{
  __shared__ int   ids[16];
  __shared__ float ls[4];
  const int tid = threadIdx.x;
  const int n0  = blockIdx.x * 16;

  if (tid < 16) ids[tid] = idxw[n0 + tid];
  __syncthreads();

  // zq + loss: row p = tid>>4, d0 = (tid&15)*4
  const int p  = tid >> 4;
  const int d0 = (tid & 15) * 4;
  const int id = ids[p];
  float4 c4 = *(const float4*)(cb + (size_t)id * 64 + d0);
  const size_t zoff = (size_t)(n0 + p) * 64 + d0;
  float4 z4 = *(const float4*)(ze + zoff);
  float dx = c4.x - z4.x, dy = c4.y - z4.y;
  float dz = c4.z - z4.z, dw = c4.w - z4.w;
  float lsum = fmaf(dx, dx, fmaf(dy, dy, fmaf(dz, dz, dw * dw)));
  nt_store4(zq_out + zoff, c4.x, c4.y, c4.z, c4.w);

  #pragma unroll
  for (int off = 32; off; off >>= 1) lsum += __shfl_down(lsum, off, 64);
  if ((tid & 63) == 0) ls[tid >> 6] = lsum;

  // encodings: 16 rows x 512 = 2048 float4s, 8 per thread
  #pragma unroll
  for (int k = 0; k < 8; k++) {
    int i = k * 256 + tid;
    int r = i >> 7;
    int c = (i & 127) * 4;
    int idr = ids[r];
    nt_store4(enc + (size_t)(n0 + r) * 512 + c,
              (c     == idr) ? 1.0f : 0.0f,
              (c + 1 == idr) ? 1.0f : 0.0f,
              (c + 2 == idr) ? 1.0f : 0.0f,
              (c + 3 == idr) ? 1.0f : 0.0f);
  }

  __syncthreads();
  if (tid == 0) atomicAdd(loss_accum, ls[0] + ls[1] + ls[2] + ls[3]);
}

__global__ __launch_bounds__(256) void fin_k(
    const int* __restrict__ counts, const float* __restrict__ loss_accum,
    float* __restrict__ loss_out, float* __restrict__ perp_out)
{
  __shared__ float sd[256];
  const int tid = threadIdx.x;
  float h = 0.f;
  for (int k = tid; k < 512; k += 256) {
    float em = (float)counts[k] * (1.0f / 65536.0f);
    h += em * logf(em + 1e-10f);
  }
  sd[tid] = h;
  __syncthreads();
  for (int s = 128; s; s >>= 1) {
    if (tid < s) sd[tid] += sd[tid + s];
    __syncthreads();
  }
  if (tid == 0) {
    *perp_out = expf(-sd[0]);
    *loss_out = *loss_accum * 1.25f / 4194304.f;
  }
}

// ---------------------------------------------------------------------------
extern "C" void kernel_launch(void* const* d_in, const int* in_sizes, int n_in,
                              void* d_out, int out_size, void* d_ws, size_t ws_size,
                              hipStream_t stream)
{
  const float* x    = (const float*)d_in[0];
  const float* w1   = (const float*)d_in[1];
  const float* b1   = (const float*)d_in[2];
  const float* w2   = (const float*)d_in[3];
  const float* b2   = (const float*)d_in[4];
  const float* w3   = (const float*)d_in[5];
  const float* b3   = (const float*)d_in[6];
  const float* r0a  = (const float*)d_in[7];
  const float* r0b  = (const float*)d_in[8];
  const float* r1a  = (const float*)d_in[9];
  const float* r1b  = (const float*)d_in[10];
  const float* wout = (const float*)d_in[11];
  const float* bout = (const float*)d_in[12];
  const float* wpq  = (const float*)d_in[13];
  const float* bpq  = (const float*)d_in[14];
  const float* cb   = (const float*)d_in[15];

  float* out = (float*)d_out;
  float* f   = (float*)d_ws;

  float* slotA  = f;                       // h1: [64][2050][64]
  float* slotB1 = f + 8396800;             // h2 then h5: [64][1026][128]
  float* slotB2 = f + 16801792;            // h3 then h7
  float* slotC  = f + 25206784;            // h4 then h6: [64][1026][64]
  float* Wcf    = f + 29409280;            // 8192
  float* bc     = f + 29417472;            // 64
  float* cnormd = f + 29417536;            // 512
  int*   counts = (int*)(f + 29418048);    // 512
  float* lossa  = f + 29418560;            // 1
  short* AB     = (short*)(f + 29418576);  // 516096 shorts
  short* A1 = AB;
  short* A2 = AB + 49152;
  short* A3 = AB + 147456;
  short* A4 = AB + 294912;
  short* A5 = AB + 368640;
  short* A6 = AB + 393216;
  short* A7 = AB + 466944;
  short* A8 = AB + 491520;
  short* Acb = (short*)(f + 29676624);     // 98304 shorts (192 KB)
  int*   idxw = (int*)(f + 29725776);      // 65536 ints

  // output layout (floats): loss | z_q_st | perp | z_e | encodings | indices
  float* loss_out = out;
  float* zq_out   = out + 1;
  float* perp_out = out + 4194305;
  float* ze_out   = out + 4194306;
  float* enc_out  = out + 8388610;
  float* idx_out  = out + 41943042;

  prep_small<<<dim3(1), dim3(256), 0, stream>>>(wout, bout, wpq, bpq, cb,
                                                Wcf, bc, cnormd);
  prep_w_all<<<dim3(300), dim3(256), 0, stream>>>(w1, w2, w3, r0a, r0b, r1a,
                                                  r1b, Wcf, cb,
                                                  A1, A2, A3, A4, A5, A6, A7,
                                                  A8, Acb);
  zero_guards<<<dim3(32), dim3(256), 0, stream>>>(slotA, slotB1, slotB2, slotC);
  hipMemsetAsync(counts, 0, 2052, stream);

  conv_mfma<64, 4, 2, false, true, false, true, false>
      <<<dim3(32, 64, 1), dim3(256), 0, stream>>>(x, A1, b1, nullptr, slotA,
                                                  4096, 2048, 4);
  conv_mfma<64, 4, 2, true, true, false, false, false>
      <<<dim3(16, 64, 2), dim3(256), 0, stream>>>(slotA, A2, b2, nullptr, slotB1,
                                                  2048, 1024, 8);
  conv_mfma<128, 3, 1, true, true, false, false, false>
      <<<dim3(16, 64, 2), dim3(256), 0, stream>>>(slotB1, A3, b3, nullptr, slotB2,
                                                  1024, 1024, 8);
  conv_mfma<128, 3, 1, true, false, false, false, false>
      <<<dim3(16, 64, 1), dim3(256), 0, stream>>>(slotB2, A4, nullptr, nullptr,
                                                  slotC, 1024, 1024, 4);
  conv_mfma<64, 1, 1, true, false, true, false, false>
      <<<dim3(16, 64, 2), dim3(256), 0, stream>>>(slotC, A5, nullptr, slotB2,
                                                  slotB1, 1024, 1024, 8);
  conv_mfma<128, 3, 1, true, false, false, false, false>
      <<<dim3(16, 64, 1), dim3(256), 0, stream>>>(slotB1, A6, nullptr, nullptr,
                                                  slotC, 1024, 1024, 4);
  conv_mfma<64, 1, 1, true, false, true, false, false>
      <<<dim3(16, 64, 2), dim3(256), 0, stream>>>(slotC, A7, nullptr, slotB1,
                                                  slotB2, 1024, 1024, 8);
  conv_mfma<128, 1, 1, true, true, false, false, true>
      <<<dim3(16, 64, 1), dim3(256), 0, stream>>>(slotB2, A8, bc, nullptr,
                                                  ze_out, 1024, 1024, 4);

  vq_argmax<<<dim3(512), dim3(256), 0, stream>>>(ze_out, cnormd, Acb,
                                                 idx_out, idxw, counts);
  vq_write<<<dim3(4096), dim3(256), 0, stream>>>(ze_out, cb, idxw,
                                                 zq_out, enc_out, lossa);
  fin_k<<<dim3(1), dim3(256), 0, stream>>>(counts, lossa, loss_out, perp_out);
}